// Round 4
// baseline (681.459 us; speedup 1.0000x reference)
//
#include <hip/hip_runtime.h>
#include <math.h>

// ---------------------------------------------------------------------------
// SpanConsistencyNetwork — MI355X (gfx950), round 4
// m201-style 8-phase schedule: per K-tile 4 phases × {ds_read frags, 2 stage
// loads, barrier, lgkmcnt(0), setprio+16 MFMA, barrier}; (tile,ks)-half
// staging, counted vmcnt(8) (tail 8/4/0); running-pointer addressing.
// ws layout unchanged from R3 (total 242,745,344 B).
// ---------------------------------------------------------------------------

typedef __bf16 bf16x8 __attribute__((ext_vector_type(8)));
typedef float f32x4 __attribute__((ext_vector_type(4)));

#define NEG_INF_VAL (-10000.0f)

__device__ __forceinline__ unsigned short f2bf(float f) {
  union { float f; unsigned u; } v; v.f = f;
  unsigned r = v.u + 0x7fffu + ((v.u >> 16) & 1u);   // RNE
  return (unsigned short)(r >> 16);
}
__device__ __forceinline__ float bf2f(unsigned short b) {
  union { unsigned u; float f; } v; v.u = ((unsigned)b) << 16;
  return v.f;
}
__device__ __forceinline__ float gelu_erf(float x) {
  return 0.5f * x * (1.0f + erff(x * 0.7071067811865476f));
}
__device__ __forceinline__ float gelu_fast(float x) {
  float u = 0.7978845608f * x * (1.0f + 0.044715f * x * x);
  float e = __expf(-2.0f * fabsf(u));
  float t = (1.0f - e) / (1.0f + e);
  t = copysignf(t, u);
  return 0.5f * x * (1.0f + t);
}

// ---- h fp32 -> bf16 ----
__global__ __launch_bounds__(256) void k_f32_to_bf16x4(
    const float* __restrict__ in, unsigned short* __restrict__ out, int n4) {
  int i = blockIdx.x * 256 + threadIdx.x;
  if (i >= n4) return;
  float4 v = reinterpret_cast<const float4*>(in)[i];
  ushort4 o;
  o.x = f2bf(v.x); o.y = f2bf(v.y); o.z = f2bf(v.z); o.w = f2bf(v.w);
  reinterpret_cast<ushort4*>(out)[i] = o;
}

// ---- tiled transpose: W [M][K][C] f32 -> Wt [M][C][K] bf16 ----
__global__ __launch_bounds__(256) void k_transpose_tiled(
    const float* __restrict__ W, unsigned short* __restrict__ Wt,
    int K, int C) {
  __shared__ float tile[32][33];
  const int m = blockIdx.z;
  const int c0 = blockIdx.x * 32, k0 = blockIdx.y * 32;
  const int tx = threadIdx.x & 31, ty = threadIdx.x >> 5;
  const float* Wm = W + (size_t)m * K * C;
#pragma unroll
  for (int r = ty; r < 32; r += 8)
    tile[r][tx] = Wm[(size_t)(k0 + r) * C + c0 + tx];
  __syncthreads();
  unsigned short* Wtm = Wt + (size_t)m * C * K;
#pragma unroll
  for (int r = ty; r < 32; r += 8)
    Wtm[(size_t)(c0 + r) * K + k0 + tx] = f2bf(tile[tx][r]);
}

#define STAGE(GP, LP)                                                        \
  __builtin_amdgcn_global_load_lds(                                          \
      (const __attribute__((address_space(1))) void*)(GP),                   \
      (__attribute__((address_space(3))) void*)(LP), 16, 0, 0)

// one phase: ds_read frags (compile-time offsets), 2 stage loads, barrier,
// lgkmcnt(0), 16 MFMA, [vmcnt], barrier.
// TILE(SLOT, DO_S1 (stage ks1(t+1)), DO_S0 (stage ks0(t+2)), VM1, VM3)
#define TILE(SLOT, DO_S1, DO_S0, VM1, VM3)                                   \
  {                                                                          \
    bf16x8 af[4], bfr[4];                                                    \
    /* ---- q0: ks0, i 0-3 ---- */                                           \
    _Pragma("unroll") for (int j = 0; j < 4; ++j)                            \
      bfr[j] = *reinterpret_cast<const bf16x8*>(                             \
          &Bs[SLOT][(wc * 4 + j) * 1024 + l8]);                              \
    _Pragma("unroll") for (int i = 0; i < 4; ++i)                            \
      af[i] = *reinterpret_cast<const bf16x8*>(                              \
          &As[SLOT][(wr * 8 + i) * 1024 + l8]);                              \
    if (DO_S1) {                                                             \
      STAGE(pA0 + 96, &As[1 - (SLOT)][(0 * 8 + w) * 1024 + 512 + l8]);       \
      STAGE(pA1 + 96, &As[1 - (SLOT)][(1 * 8 + w) * 1024 + 512 + l8]);       \
    }                                                                        \
    __builtin_amdgcn_s_barrier();                                            \
    __builtin_amdgcn_sched_barrier(0);                                       \
    asm volatile("s_waitcnt lgkmcnt(0)" ::: "memory");                       \
    __builtin_amdgcn_sched_barrier(0);                                       \
    __builtin_amdgcn_s_setprio(1);                                           \
    _Pragma("unroll") for (int i = 0; i < 4; ++i)                            \
      _Pragma("unroll") for (int j = 0; j < 4; ++j)                          \
        acc[i][j] = __builtin_amdgcn_mfma_f32_16x16x32_bf16(                 \
            af[i], bfr[j], acc[i][j], 0, 0, 0);                              \
    __builtin_amdgcn_s_setprio(0);                                           \
    __builtin_amdgcn_sched_barrier(0);                                       \
    __builtin_amdgcn_s_barrier();                                            \
    __builtin_amdgcn_sched_barrier(0);                                       \
    /* ---- q1: ks0, i 4-7 ---- */                                           \
    _Pragma("unroll") for (int i = 0; i < 4; ++i)                            \
      af[i] = *reinterpret_cast<const bf16x8*>(                              \
          &As[SLOT][(wr * 8 + 4 + i) * 1024 + l8]);                          \
    if (DO_S1) {                                                             \
      STAGE(pB0 + 96, &Bs[1 - (SLOT)][(0 * 8 + w) * 1024 + 512 + l8]);       \
      STAGE(pB1 + 96, &Bs[1 - (SLOT)][(1 * 8 + w) * 1024 + 512 + l8]);       \
    }                                                                        \
    __builtin_amdgcn_s_barrier();                                            \
    __builtin_amdgcn_sched_barrier(0);                                       \
    asm volatile("s_waitcnt lgkmcnt(0)" ::: "memory");                       \
    __builtin_amdgcn_sched_barrier(0);                                       \
    __builtin_amdgcn_s_setprio(1);                                           \
    _Pragma("unroll") for (int i = 0; i < 4; ++i)                            \
      _Pragma("unroll") for (int j = 0; j < 4; ++j)                          \
        acc[4 + i][j] = __builtin_amdgcn_mfma_f32_16x16x32_bf16(             \
            af[i], bfr[j], acc[4 + i][j], 0, 0, 0);                          \
    __builtin_amdgcn_s_setprio(0);                                           \
    __builtin_amdgcn_sched_barrier(0);                                       \
    asm volatile("s_waitcnt vmcnt(" VM1 ")" ::: "memory");                   \
    __builtin_amdgcn_sched_barrier(0);                                       \
    __builtin_amdgcn_s_barrier();                                            \
    __builtin_amdgcn_sched_barrier(0);                                       \
    /* ---- q2: ks1, i 0-3 ---- */                                           \
    _Pragma("unroll") for (int j = 0; j < 4; ++j)                            \
      bfr[j] = *reinterpret_cast<const bf16x8*>(                             \
          &Bs[SLOT][(wc * 4 + j) * 1024 + 512 + l8]);                        \
    _Pragma("unroll") for (int i = 0; i < 4; ++i)                            \
      af[i] = *reinterpret_cast<const bf16x8*>(                              \
          &As[SLOT][(wr * 8 + i) * 1024 + 512 + l8]);                        \
    if (DO_S0) {                                                             \
      STAGE(pA0 + 128, &As[SLOT][(0 * 8 + w) * 1024 + l8]);                  \
      STAGE(pA1 + 128, &As[SLOT][(1 * 8 + w) * 1024 + l8]);                  \
    }                                                                        \
    __builtin_amdgcn_s_barrier();                                            \
    __builtin_amdgcn_sched_barrier(0);                                       \
    asm volatile("s_waitcnt lgkmcnt(0)" ::: "memory");                       \
    __builtin_amdgcn_sched_barrier(0);                                       \
    __builtin_amdgcn_s_setprio(1);                                           \
    _Pragma("unroll") for (int i = 0; i < 4; ++i)                            \
      _Pragma("unroll") for (int j = 0; j < 4; ++j)                          \
        acc[i][j] = __builtin_amdgcn_mfma_f32_16x16x32_bf16(                 \
            af[i], bfr[j], acc[i][j], 0, 0, 0);                              \
    __builtin_amdgcn_s_setprio(0);                                           \
    __builtin_amdgcn_sched_barrier(0);                                       \
    __builtin_amdgcn_s_barrier();                                            \
    __builtin_amdgcn_sched_barrier(0);                                       \
    /* ---- q3: ks1, i 4-7 ---- */                                           \
    _Pragma("unroll") for (int i = 0; i < 4; ++i)                            \
      af[i] = *reinterpret_cast<const bf16x8*>(                              \
          &As[SLOT][(wr * 8 + 4 + i) * 1024 + 512 + l8]);                    \
    if (DO_S0) {                                                             \
      STAGE(pB0 + 128, &Bs[SLOT][(0 * 8 + w) * 1024 + l8]);                  \
      STAGE(pB1 + 128, &Bs[SLOT][(1 * 8 + w) * 1024 + l8]);                  \
    }                                                                        \
    __builtin_amdgcn_s_barrier();                                            \
    __builtin_amdgcn_sched_barrier(0);                                       \
    asm volatile("s_waitcnt lgkmcnt(0)" ::: "memory");                       \
    __builtin_amdgcn_sched_barrier(0);                                       \
    __builtin_amdgcn_s_setprio(1);                                           \
    _Pragma("unroll") for (int i = 0; i < 4; ++i)                            \
      _Pragma("unroll") for (int j = 0; j < 4; ++j)                          \
        acc[4 + i][j] = __builtin_amdgcn_mfma_f32_16x16x32_bf16(             \
            af[i], bfr[j], acc[4 + i][j], 0, 0, 0);                          \
    __builtin_amdgcn_s_setprio(0);                                           \
    __builtin_amdgcn_sched_barrier(0);                                       \
    asm volatile("s_waitcnt vmcnt(" VM3 ")" ::: "memory");                   \
    __builtin_amdgcn_sched_barrier(0);                                       \
    __builtin_amdgcn_s_barrier();                                            \
    __builtin_amdgcn_sched_barrier(0);                                       \
    pA0 += 64; pA1 += 64; pB0 += 64; pB1 += 64;                              \
  }

// ---- 256x256 GEMM, 8-phase pipeline; FUSE_SCORES fuses gelu->dot(W3) ----
template <bool FUSE_SCORES, int NT>
__global__ __launch_bounds__(512) void k_gemm256(
    const unsigned short* __restrict__ A, int lda, int aOffPerM,
    const unsigned short* __restrict__ Bt, int K,          // ldb == K
    const float* __restrict__ bias,
    unsigned short* __restrict__ C, int ldc,
    const float* __restrict__ W3, const float* __restrict__ b3,
    float* __restrict__ scoresOut,
    int tilesPerM, int colsPerM, int nColTiles) {
  __shared__ __align__(16) unsigned short As[2][16384];
  __shared__ __align__(16) unsigned short Bs[2][16384];
  __shared__ float sc[256];
  const int t512 = threadIdx.x;
  const int w = t512 >> 6, l = t512 & 63;
  const int wr = w >> 2, wc = w & 3;
  const int l8 = l * 8;

  const int nwg = gridDim.x;
  const int cpx = nwg >> 3;
  const int bid = blockIdx.x;
  const int swz = (bid & 7) * cpx + (bid >> 3);      // bijective: nwg % 8 == 0
  const int ct = swz % nColTiles, rt = swz / nColTiles;
  const int m = ct / tilesPerM, cb = ct - m * tilesPerM;
  const int gcol0 = m * colsPerM + cb * 256;
  const int row0 = rt * 256;
  const unsigned short* Am = A + (size_t)m * aOffPerM;

  if (FUSE_SCORES && t512 < 256) sc[t512] = 0.f;

  f32x4 acc[8][4] = {};

  // running staging pointers (element ptrs at current tile's k-base)
  const int r = l & 15;
  const int c8 = (l >> 4) * 8;
  const unsigned short* pA0 = Am + (size_t)(row0 + w * 16 + r) * lda + c8;
  const unsigned short* pA1 = Am + (size_t)(row0 + 128 + w * 16 + r) * lda + c8;
  const unsigned short* pB0 = Bt + (size_t)(gcol0 + w * 16 + r) * (size_t)K + c8;
  const unsigned short* pB1 = Bt + (size_t)(gcol0 + 128 + w * 16 + r) * (size_t)K + c8;

  // prologue: stage ks0(0), ks1(0), ks0(1) — 12 loads in FIFO order
  STAGE(pA0,      &As[0][(0 * 8 + w) * 1024 + l8]);
  STAGE(pA1,      &As[0][(1 * 8 + w) * 1024 + l8]);
  STAGE(pB0,      &Bs[0][(0 * 8 + w) * 1024 + l8]);
  STAGE(pB1,      &Bs[0][(1 * 8 + w) * 1024 + l8]);
  STAGE(pA0 + 32, &As[0][(0 * 8 + w) * 1024 + 512 + l8]);
  STAGE(pA1 + 32, &As[0][(1 * 8 + w) * 1024 + 512 + l8]);
  STAGE(pB0 + 32, &Bs[0][(0 * 8 + w) * 1024 + 512 + l8]);
  STAGE(pB1 + 32, &Bs[0][(1 * 8 + w) * 1024 + 512 + l8]);
  STAGE(pA0 + 64, &As[1][(0 * 8 + w) * 1024 + l8]);
  STAGE(pA1 + 64, &As[1][(1 * 8 + w) * 1024 + l8]);
  STAGE(pB0 + 64, &Bs[1][(0 * 8 + w) * 1024 + l8]);
  STAGE(pB1 + 64, &Bs[1][(1 * 8 + w) * 1024 + l8]);
  asm volatile("s_waitcnt vmcnt(8)" ::: "memory");   // ks0(0) landed
  __builtin_amdgcn_sched_barrier(0);
  __builtin_amdgcn_s_barrier();
  __builtin_amdgcn_sched_barrier(0);

#pragma unroll 1
  for (int t = 0; t < NT - 2; t += 2) {
    TILE(0, 1, 1, "8", "8");
    TILE(1, 1, 1, "8", "8");
  }
  TILE(0, 1, 0, "8", "4");   // tile NT-2 (NT even -> slot 0)
  TILE(1, 0, 0, "0", "0");   // tile NT-1

  if (!FUSE_SCORES) {
    const int orow = (l >> 4) * 4, ocol = l & 15;
#pragma unroll
    for (int i = 0; i < 8; ++i)
#pragma unroll
      for (int j = 0; j < 4; ++j) {
        const int gc = gcol0 + wc * 64 + j * 16 + ocol;
        const float bv = bias[gc];
        const int gr0 = row0 + wr * 128 + i * 16 + orow;
#pragma unroll
        for (int rr = 0; rr < 4; ++rr) {
          float v = gelu_fast(acc[i][j][rr] + bv);
          C[(size_t)(gr0 + rr) * ldc + gc] = f2bf(v);
        }
      }
  } else {
    const int ocol = l & 15;
#pragma unroll
    for (int i = 0; i < 8; ++i) {
      float rs[4] = {0.f, 0.f, 0.f, 0.f};
#pragma unroll
      for (int j = 0; j < 4; ++j) {
        const int cl = wc * 64 + j * 16 + ocol;
        const float bv = bias[m * 256 + cl];
        const float w3v = W3[m * 256 + cl];
#pragma unroll
        for (int rr = 0; rr < 4; ++rr)
          rs[rr] += gelu_fast(acc[i][j][rr] + bv) * w3v;
      }
#pragma unroll
      for (int s = 1; s < 16; s <<= 1)
#pragma unroll
        for (int rr = 0; rr < 4; ++rr)
          rs[rr] += __shfl_xor(rs[rr], s);
      if (ocol == 0) {
        const int lr0 = wr * 128 + i * 16 + (l >> 4) * 4;
#pragma unroll
        for (int rr = 0; rr < 4; ++rr)
          atomicAdd(&sc[lr0 + rr], rs[rr]);
      }
    }
    __syncthreads();
    if (t512 < 256)
      scoresOut[(size_t)m * 32768 + row0 + t512] = sc[t512] + b3[m];
  }
}

// ---- span consistency: block per (b, m) ----
__global__ __launch_bounds__(256) void k_span(
    const float* __restrict__ scores,   // [5][16][2048]
    const int* __restrict__ mask,       // [16][2048]
    const float* __restrict__ gamma,    // [5]
    const float* __restrict__ wlog,     // [5][15]
    float* __restrict__ logits) {       // [16][2048][5]
  const int b = blockIdx.x, m = blockIdx.y;
  const int tid = threadIdx.x;
  __shared__ float masked[2048], mins[2048], boost[2048];
  __shared__ float ww[14];
  if (tid == 0) {
    float mx = -1e30f;
    for (int i = 0; i < 15; i++) mx = fmaxf(mx, wlog[m * 15 + i]);
    float e[15], sum = 0.f;
    for (int i = 0; i < 15; i++) { e[i] = expf(wlog[m * 15 + i] - mx); sum += e[i]; }
    for (int i = 0; i < 14; i++) ww[i] = e[i] / sum;
  }
  const float* srow = scores + ((size_t)m * 16 + b) * 2048;
  const int* mrow = mask + (size_t)b * 2048;
  for (int i = tid; i < 2048; i += 256) {
    float s = srow[i];
    float mk = (mrow[i] == 0) ? NEG_INF_VAL : s;
    masked[i] = mk; mins[i] = mk; boost[i] = mk;
  }
  __syncthreads();
  for (int w2 = 2; w2 <= 15; w2++) {
    for (int s = tid; s <= 2048 - w2; s += 256)
      mins[s] = fminf(mins[s], masked[s + w2 - 1]);
    __syncthreads();
    float c = ww[w2 - 2];
    for (int i = tid; i < 2048; i += 256) {
      int lo = i - w2 + 1; if (lo < 0) lo = 0;
      int hi = i; if (hi > 2048 - w2) hi = 2048 - w2;
      float mx = -1e30f;
      for (int s = lo; s <= hi; s++) mx = fmaxf(mx, mins[s]);
      boost[i] = fmaxf(boost[i], mx * c);
    }
    __syncthreads();
  }
  float g = gamma[m];
  for (int i = tid; i < 2048; i += 256)
    logits[((size_t)b * 2048 + i) * 5 + m] = srow[i] + g * boost[i];
}

// ---- cross-marker refinement ----
__global__ __launch_bounds__(256) void k_cross(
    const float* __restrict__ logits, const float* __restrict__ corr,
    const float* __restrict__ cw1, const float* __restrict__ cb1,
    const float* __restrict__ cw2, const float* __restrict__ cb2,
    const float* __restrict__ gate, float* __restrict__ out) {
  __shared__ float s_corr[25], s_cw1[320], s_cb1[64], s_cw2[320], s_cb2[5];
  int tid = threadIdx.x;
  if (tid < 25) s_corr[tid] = corr[tid];
  if (tid < 64) s_cb1[tid] = cb1[tid];
  if (tid < 5)  s_cb2[tid] = cb2[tid];
  for (int i = tid; i < 320; i += 256) { s_cw1[i] = cw1[i]; s_cw2[i] = cw2[i]; }
  __syncthreads();
  int t = blockIdx.x * 256 + tid;
  float lg[5], pr[5];
#pragma unroll
  for (int m = 0; m < 5; m++) {
    lg[m] = logits[(size_t)t * 5 + m];
    pr[m] = 1.f / (1.f + expf(-lg[m]));
  }
  float co[5];
#pragma unroll
  for (int j = 0; j < 5; j++) {
    float s = 0.f;
#pragma unroll
    for (int mm = 0; mm < 5; mm++) s += pr[mm] * s_corr[mm * 5 + j];
    co[j] = s;
  }
  float ref[5];
#pragma unroll
  for (int m = 0; m < 5; m++) ref[m] = s_cb2[m];
  for (int k = 0; k < 64; k++) {
    float h = s_cb1[k];
#pragma unroll
    for (int j = 0; j < 5; j++) h += co[j] * s_cw1[j * 64 + k];
    h = gelu_erf(h);
#pragma unroll
    for (int m = 0; m < 5; m++) ref[m] += h * s_cw2[k * 5 + m];
  }
  float sg = 1.f / (1.f + expf(-gate[0]));
#pragma unroll
  for (int m = 0; m < 5; m++) out[(size_t)t * 5 + m] = lg[m] + sg * ref[m];
}

extern "C" void kernel_launch(void* const* d_in, const int* in_sizes, int n_in,
                              void* d_out, int out_size, void* d_ws, size_t ws_size,
                              hipStream_t stream) {
  const float* h     = (const float*)d_in[0];
  const int*   mask  = (const int*)d_in[1];
  const float* W1    = (const float*)d_in[2];
  const float* b1    = (const float*)d_in[3];
  const float* W2    = (const float*)d_in[4];
  const float* b2    = (const float*)d_in[5];
  const float* W3    = (const float*)d_in[6];
  const float* b3    = (const float*)d_in[7];
  const float* gamma = (const float*)d_in[8];
  const float* wlog  = (const float*)d_in[9];
  const float* corr  = (const float*)d_in[10];
  const float* cw1   = (const float*)d_in[11];
  const float* cb1   = (const float*)d_in[12];
  const float* cw2   = (const float*)d_in[13];
  const float* cb2   = (const float*)d_in[14];
  const float* gate  = (const float*)d_in[15];
  float* out = (float*)d_out;

  char* ws = (char*)d_ws;
  unsigned short* hb  = (unsigned short*)(ws);
  unsigned short* W1t = (unsigned short*)(ws + 67108864);
  unsigned short* W2t = (unsigned short*)(ws + 72351744);
  unsigned short* t1  = (unsigned short*)(ws + 73662464);
  float* scores       = (float*)(ws + 241434624);
  float* logits       = (float*)(ws + 242089984);

  k_f32_to_bf16x4<<<33554432 / 4 / 256, 256, 0, stream>>>(h, hb, 33554432 / 4);
  k_transpose_tiled<<<dim3(16, 32, 5), 256, 0, stream>>>(W1, W1t, 1024, 512);
  k_transpose_tiled<<<dim3(8, 16, 5), 256, 0, stream>>>(W2, W2t, 512, 256);

  // GEMM1: hb[32768,1024] x W1t[2560,1024]^T -> t1 (gelu). NT=16.
  k_gemm256<false, 16><<<1280, 512, 0, stream>>>(
      hb, 1024, 0, W1t, 1024, b1, t1, 2560,
      nullptr, nullptr, nullptr, 10, 2560, 10);
  // GEMM2+scores: per m, t1[:, m*512 +: 512] x W2t_m^T -> gelu -> dot W3[m]. NT=8.
  k_gemm256<true, 8><<<640, 512, 0, stream>>>(
      t1, 2560, 512, W2t, 512, b2, nullptr, 0,
      W3, b3, scores, 1, 256, 5);

  k_span<<<dim3(16, 5), 256, 0, stream>>>(scores, mask, gamma, wlog, logits);
  k_cross<<<32768 / 256, 256, 0, stream>>>(logits, corr, cw1, cb1, cw2, cb2, gate, out);
}

// Round 5
// 666.442 us; speedup vs baseline: 1.0225x; 1.0225x over previous
//
#include <hip/hip_runtime.h>
#include <math.h>

// ---------------------------------------------------------------------------
// SpanConsistencyNetwork — MI355X (gfx950), round 5
// R4 + one-quarter read-ahead: ds_reads issued in quarter q feed the MFMA of
// quarter q+1, so the LDS drain overlaps the matrix pipe (m201's mechanism).
// Counted lgkmcnt(4/8/4/0); vmcnt(6) @q0-end + vmcnt(8) @q3-end (re-derived).
// ws layout unchanged from R3 (total 242,745,344 B).
// ---------------------------------------------------------------------------

typedef __bf16 bf16x8 __attribute__((ext_vector_type(8)));
typedef float f32x4 __attribute__((ext_vector_type(4)));

#define NEG_INF_VAL (-10000.0f)

__device__ __forceinline__ unsigned short f2bf(float f) {
  union { float f; unsigned u; } v; v.f = f;
  unsigned r = v.u + 0x7fffu + ((v.u >> 16) & 1u);   // RNE
  return (unsigned short)(r >> 16);
}
__device__ __forceinline__ float bf2f(unsigned short b) {
  union { unsigned u; float f; } v; v.u = ((unsigned)b) << 16;
  return v.f;
}
__device__ __forceinline__ float gelu_erf(float x) {
  return 0.5f * x * (1.0f + erff(x * 0.7071067811865476f));
}
__device__ __forceinline__ float gelu_fast(float x) {
  float u = 0.7978845608f * x * (1.0f + 0.044715f * x * x);
  float e = __expf(-2.0f * fabsf(u));
  float t = (1.0f - e) / (1.0f + e);
  t = copysignf(t, u);
  return 0.5f * x * (1.0f + t);
}

// ---- h fp32 -> bf16 ----
__global__ __launch_bounds__(256) void k_f32_to_bf16x4(
    const float* __restrict__ in, unsigned short* __restrict__ out, int n4) {
  int i = blockIdx.x * 256 + threadIdx.x;
  if (i >= n4) return;
  float4 v = reinterpret_cast<const float4*>(in)[i];
  ushort4 o;
  o.x = f2bf(v.x); o.y = f2bf(v.y); o.z = f2bf(v.z); o.w = f2bf(v.w);
  reinterpret_cast<ushort4*>(out)[i] = o;
}

// ---- tiled transpose: W [M][K][C] f32 -> Wt [M][C][K] bf16 ----
__global__ __launch_bounds__(256) void k_transpose_tiled(
    const float* __restrict__ W, unsigned short* __restrict__ Wt,
    int K, int C) {
  __shared__ float tile[32][33];
  const int m = blockIdx.z;
  const int c0 = blockIdx.x * 32, k0 = blockIdx.y * 32;
  const int tx = threadIdx.x & 31, ty = threadIdx.x >> 5;
  const float* Wm = W + (size_t)m * K * C;
#pragma unroll
  for (int r = ty; r < 32; r += 8)
    tile[r][tx] = Wm[(size_t)(k0 + r) * C + c0 + tx];
  __syncthreads();
  unsigned short* Wtm = Wt + (size_t)m * C * K;
#pragma unroll
  for (int r = ty; r < 32; r += 8)
    Wtm[(size_t)(c0 + r) * K + k0 + tx] = f2bf(tile[tx][r]);
}

#define STAGE(GP, LP)                                                        \
  __builtin_amdgcn_global_load_lds(                                          \
      (const __attribute__((address_space(1))) void*)(GP),                   \
      (__attribute__((address_space(3))) void*)(LP), 16, 0, 0)

#define MFMA16(OFF, AF, BF)                                                  \
    _Pragma("unroll") for (int i = 0; i < 4; ++i)                            \
      _Pragma("unroll") for (int j = 0; j < 4; ++j)                          \
        acc[(OFF) + i][j] = __builtin_amdgcn_mfma_f32_16x16x32_bf16(         \
            AF[i], BF[j], acc[(OFF) + i][j], 0, 0, 0);

#define BARRIER_PAIR()                                                       \
    __builtin_amdgcn_sched_barrier(0);                                       \
    __builtin_amdgcn_s_barrier();                                            \
    __builtin_amdgcn_sched_barrier(0);

// One K-tile = 4 quarters. Reads in quarter q feed MFMA of quarter q+1.
// q0: read ks0 frags (12) ; stage A-ks1(t+1) ; vmcnt(VMQ0) ; bar ; lgkm(4) ; MFMA q0 ; bar
// q1: read bfrB+afA-ks1 (8); stage B-ks1(t+1) ;              bar ; lgkm(8) ; MFMA q1 ; bar
// q2: read afB-ks1 (4)     ; stage A-ks0(t+2) ;              bar ; lgkm(4) ; MFMA q2 ; bar
// q3:                        stage B-ks0(t+2) ; vmcnt(VMQ3) ; bar ; lgkm(0) ; MFMA q3 ; bar
#define TILE2(SLOT, DO_S1, DO_S0, VMQ0, VMQ3)                                \
  {                                                                          \
    bf16x8 afA[4], afB[4], bfrA[4], bfrB[4];                                 \
    /* ---- q0 ---- */                                                       \
    _Pragma("unroll") for (int j = 0; j < 4; ++j)                            \
      bfrA[j] = *reinterpret_cast<const bf16x8*>(                            \
          &Bs[SLOT][(wc * 4 + j) * 1024 + l8]);                              \
    _Pragma("unroll") for (int i = 0; i < 4; ++i)                            \
      afA[i] = *reinterpret_cast<const bf16x8*>(                             \
          &As[SLOT][(wr * 8 + i) * 1024 + l8]);                              \
    _Pragma("unroll") for (int i = 0; i < 4; ++i)                            \
      afB[i] = *reinterpret_cast<const bf16x8*>(                             \
          &As[SLOT][(wr * 8 + 4 + i) * 1024 + l8]);                          \
    if (DO_S1) {                                                             \
      STAGE(pA0 + 96, &As[1 - (SLOT)][(0 * 8 + w) * 1024 + 512 + l8]);       \
      STAGE(pA1 + 96, &As[1 - (SLOT)][(1 * 8 + w) * 1024 + 512 + l8]);       \
    }                                                                        \
    asm volatile("s_waitcnt vmcnt(" VMQ0 ")" ::: "memory");                  \
    BARRIER_PAIR();                                                          \
    asm volatile("s_waitcnt lgkmcnt(4)" ::: "memory");                       \
    __builtin_amdgcn_sched_barrier(0);                                       \
    __builtin_amdgcn_s_setprio(1);                                           \
    MFMA16(0, afA, bfrA);                                                    \
    __builtin_amdgcn_s_setprio(0);                                           \
    BARRIER_PAIR();                                                          \
    /* ---- q1 ---- */                                                       \
    _Pragma("unroll") for (int j = 0; j < 4; ++j)                            \
      bfrB[j] = *reinterpret_cast<const bf16x8*>(                            \
          &Bs[SLOT][(wc * 4 + j) * 1024 + 512 + l8]);                        \
    _Pragma("unroll") for (int i = 0; i < 4; ++i)                            \
      afA[i] = *reinterpret_cast<const bf16x8*>(                             \
          &As[SLOT][(wr * 8 + i) * 1024 + 512 + l8]);                        \
    if (DO_S1) {                                                             \
      STAGE(pB0 + 96, &Bs[1 - (SLOT)][(0 * 8 + w) * 1024 + 512 + l8]);       \
      STAGE(pB1 + 96, &Bs[1 - (SLOT)][(1 * 8 + w) * 1024 + 512 + l8]);       \
    }                                                                        \
    BARRIER_PAIR();                                                          \
    asm volatile("s_waitcnt lgkmcnt(8)" ::: "memory");                       \
    __builtin_amdgcn_sched_barrier(0);                                       \
    __builtin_amdgcn_s_setprio(1);                                           \
    MFMA16(4, afB, bfrA);                                                    \
    __builtin_amdgcn_s_setprio(0);                                           \
    BARRIER_PAIR();                                                          \
    /* ---- q2 ---- */                                                       \
    _Pragma("unroll") for (int i = 0; i < 4; ++i)                            \
      afB[i] = *reinterpret_cast<const bf16x8*>(                             \
          &As[SLOT][(wr * 8 + 4 + i) * 1024 + 512 + l8]);                    \
    if (DO_S0) {                                                             \
      STAGE(pA0 + 128, &As[SLOT][(0 * 8 + w) * 1024 + l8]);                  \
      STAGE(pA1 + 128, &As[SLOT][(1 * 8 + w) * 1024 + l8]);                  \
    }                                                                        \
    BARRIER_PAIR();                                                          \
    asm volatile("s_waitcnt lgkmcnt(4)" ::: "memory");                       \
    __builtin_amdgcn_sched_barrier(0);                                       \
    __builtin_amdgcn_s_setprio(1);                                           \
    MFMA16(0, afA, bfrB);                                                    \
    __builtin_amdgcn_s_setprio(0);                                           \
    BARRIER_PAIR();                                                          \
    /* ---- q3 ---- */                                                       \
    if (DO_S0) {                                                             \
      STAGE(pB0 + 128, &Bs[SLOT][(0 * 8 + w) * 1024 + l8]);                  \
      STAGE(pB1 + 128, &Bs[SLOT][(1 * 8 + w) * 1024 + l8]);                  \
    }                                                                        \
    asm volatile("s_waitcnt vmcnt(" VMQ3 ")" ::: "memory");                  \
    BARRIER_PAIR();                                                          \
    asm volatile("s_waitcnt lgkmcnt(0)" ::: "memory");                       \
    __builtin_amdgcn_sched_barrier(0);                                       \
    __builtin_amdgcn_s_setprio(1);                                           \
    MFMA16(4, afB, bfrB);                                                    \
    __builtin_amdgcn_s_setprio(0);                                           \
    BARRIER_PAIR();                                                          \
    pA0 += 64; pA1 += 64; pB0 += 64; pB1 += 64;                              \
  }

// ---- 256x256 GEMM, pipelined 8-phase; FUSE_SCORES fuses gelu->dot(W3) ----
template <bool FUSE_SCORES, int NT>
__global__ __launch_bounds__(512) void k_gemm256(
    const unsigned short* __restrict__ A, int lda, int aOffPerM,
    const unsigned short* __restrict__ Bt, int K,          // ldb == K
    const float* __restrict__ bias,
    unsigned short* __restrict__ C, int ldc,
    const float* __restrict__ W3, const float* __restrict__ b3,
    float* __restrict__ scoresOut,
    int tilesPerM, int colsPerM, int nColTiles) {
  __shared__ __align__(16) unsigned short As[2][16384];
  __shared__ __align__(16) unsigned short Bs[2][16384];
  __shared__ float sc[256];
  const int t512 = threadIdx.x;
  const int w = t512 >> 6, l = t512 & 63;
  const int wr = w >> 2, wc = w & 3;
  const int l8 = l * 8;

  const int nwg = gridDim.x;
  const int cpx = nwg >> 3;
  const int bid = blockIdx.x;
  const int swz = (bid & 7) * cpx + (bid >> 3);      // bijective: nwg % 8 == 0
  const int ct = swz % nColTiles, rt = swz / nColTiles;
  const int m = ct / tilesPerM, cb = ct - m * tilesPerM;
  const int gcol0 = m * colsPerM + cb * 256;
  const int row0 = rt * 256;
  const unsigned short* Am = A + (size_t)m * aOffPerM;

  if (FUSE_SCORES && t512 < 256) sc[t512] = 0.f;

  f32x4 acc[8][4] = {};

  // running staging pointers (element ptrs at current tile's k-base)
  const int r = l & 15;
  const int c8 = (l >> 4) * 8;
  const unsigned short* pA0 = Am + (size_t)(row0 + w * 16 + r) * lda + c8;
  const unsigned short* pA1 = Am + (size_t)(row0 + 128 + w * 16 + r) * lda + c8;
  const unsigned short* pB0 = Bt + (size_t)(gcol0 + w * 16 + r) * (size_t)K + c8;
  const unsigned short* pB1 = Bt + (size_t)(gcol0 + 128 + w * 16 + r) * (size_t)K + c8;

  // prologue: stage ks0(0), ks1(0), ks0(1) — 12 loads in FIFO order
  STAGE(pA0,      &As[0][(0 * 8 + w) * 1024 + l8]);
  STAGE(pA1,      &As[0][(1 * 8 + w) * 1024 + l8]);
  STAGE(pB0,      &Bs[0][(0 * 8 + w) * 1024 + l8]);
  STAGE(pB1,      &Bs[0][(1 * 8 + w) * 1024 + l8]);
  STAGE(pA0 + 32, &As[0][(0 * 8 + w) * 1024 + 512 + l8]);
  STAGE(pA1 + 32, &As[0][(1 * 8 + w) * 1024 + 512 + l8]);
  STAGE(pB0 + 32, &Bs[0][(0 * 8 + w) * 1024 + 512 + l8]);
  STAGE(pB1 + 32, &Bs[0][(1 * 8 + w) * 1024 + 512 + l8]);
  STAGE(pA0 + 64, &As[1][(0 * 8 + w) * 1024 + l8]);
  STAGE(pA1 + 64, &As[1][(1 * 8 + w) * 1024 + l8]);
  STAGE(pB0 + 64, &Bs[1][(0 * 8 + w) * 1024 + l8]);
  STAGE(pB1 + 64, &Bs[1][(1 * 8 + w) * 1024 + l8]);
  asm volatile("s_waitcnt vmcnt(8)" ::: "memory");   // ks0(0) landed
  BARRIER_PAIR();

#pragma unroll 1
  for (int t = 0; t < NT - 2; t += 2) {
    TILE2(0, 1, 1, "6", "8");
    TILE2(1, 1, 1, "6", "8");
  }
  TILE2(0, 1, 0, "6", "4");   // tile NT-2 (NT even -> slot 0)
  TILE2(1, 0, 0, "0", "0");   // tile NT-1

  if (!FUSE_SCORES) {
    const int orow = (l >> 4) * 4, ocol = l & 15;
#pragma unroll
    for (int i = 0; i < 8; ++i)
#pragma unroll
      for (int j = 0; j < 4; ++j) {
        const int gc = gcol0 + wc * 64 + j * 16 + ocol;
        const float bv = bias[gc];
        const int gr0 = row0 + wr * 128 + i * 16 + orow;
#pragma unroll
        for (int rr = 0; rr < 4; ++rr) {
          float v = gelu_fast(acc[i][j][rr] + bv);
          C[(size_t)(gr0 + rr) * ldc + gc] = f2bf(v);
        }
      }
  } else {
    const int ocol = l & 15;
#pragma unroll
    for (int i = 0; i < 8; ++i) {
      float rs[4] = {0.f, 0.f, 0.f, 0.f};
#pragma unroll
      for (int j = 0; j < 4; ++j) {
        const int cl = wc * 64 + j * 16 + ocol;
        const float bv = bias[m * 256 + cl];
        const float w3v = W3[m * 256 + cl];
#pragma unroll
        for (int rr = 0; rr < 4; ++rr)
          rs[rr] += gelu_fast(acc[i][j][rr] + bv) * w3v;
      }
#pragma unroll
      for (int s = 1; s < 16; s <<= 1)
#pragma unroll
        for (int rr = 0; rr < 4; ++rr)
          rs[rr] += __shfl_xor(rs[rr], s);
      if (ocol == 0) {
        const int lr0 = wr * 128 + i * 16 + (l >> 4) * 4;
#pragma unroll
        for (int rr = 0; rr < 4; ++rr)
          atomicAdd(&sc[lr0 + rr], rs[rr]);
      }
    }
    __syncthreads();
    if (t512 < 256)
      scoresOut[(size_t)m * 32768 + row0 + t512] = sc[t512] + b3[m];
  }
}

// ---- span consistency: block per (b, m) ----
__global__ __launch_bounds__(256) void k_span(
    const float* __restrict__ scores,   // [5][16][2048]
    const int* __restrict__ mask,       // [16][2048]
    const float* __restrict__ gamma,    // [5]
    const float* __restrict__ wlog,     // [5][15]
    float* __restrict__ logits) {       // [16][2048][5]
  const int b = blockIdx.x, m = blockIdx.y;
  const int tid = threadIdx.x;
  __shared__ float masked[2048], mins[2048], boost[2048];
  __shared__ float ww[14];
  if (tid == 0) {
    float mx = -1e30f;
    for (int i = 0; i < 15; i++) mx = fmaxf(mx, wlog[m * 15 + i]);
    float e[15], sum = 0.f;
    for (int i = 0; i < 15; i++) { e[i] = expf(wlog[m * 15 + i] - mx); sum += e[i]; }
    for (int i = 0; i < 14; i++) ww[i] = e[i] / sum;
  }
  const float* srow = scores + ((size_t)m * 16 + b) * 2048;
  const int* mrow = mask + (size_t)b * 2048;
  for (int i = tid; i < 2048; i += 256) {
    float s = srow[i];
    float mk = (mrow[i] == 0) ? NEG_INF_VAL : s;
    masked[i] = mk; mins[i] = mk; boost[i] = mk;
  }
  __syncthreads();
  for (int w2 = 2; w2 <= 15; w2++) {
    for (int s = tid; s <= 2048 - w2; s += 256)
      mins[s] = fminf(mins[s], masked[s + w2 - 1]);
    __syncthreads();
    float c = ww[w2 - 2];
    for (int i = tid; i < 2048; i += 256) {
      int lo = i - w2 + 1; if (lo < 0) lo = 0;
      int hi = i; if (hi > 2048 - w2) hi = 2048 - w2;
      float mx = -1e30f;
      for (int s = lo; s <= hi; s++) mx = fmaxf(mx, mins[s]);
      boost[i] = fmaxf(boost[i], mx * c);
    }
    __syncthreads();
  }
  float g = gamma[m];
  for (int i = tid; i < 2048; i += 256)
    logits[((size_t)b * 2048 + i) * 5 + m] = srow[i] + g * boost[i];
}

// ---- cross-marker refinement ----
__global__ __launch_bounds__(256) void k_cross(
    const float* __restrict__ logits, const float* __restrict__ corr,
    const float* __restrict__ cw1, const float* __restrict__ cb1,
    const float* __restrict__ cw2, const float* __restrict__ cb2,
    const float* __restrict__ gate, float* __restrict__ out) {
  __shared__ float s_corr[25], s_cw1[320], s_cb1[64], s_cw2[320], s_cb2[5];
  int tid = threadIdx.x;
  if (tid < 25) s_corr[tid] = corr[tid];
  if (tid < 64) s_cb1[tid] = cb1[tid];
  if (tid < 5)  s_cb2[tid] = cb2[tid];
  for (int i = tid; i < 320; i += 256) { s_cw1[i] = cw1[i]; s_cw2[i] = cw2[i]; }
  __syncthreads();
  int t = blockIdx.x * 256 + tid;
  float lg[5], pr[5];
#pragma unroll
  for (int m = 0; m < 5; m++) {
    lg[m] = logits[(size_t)t * 5 + m];
    pr[m] = 1.f / (1.f + expf(-lg[m]));
  }
  float co[5];
#pragma unroll
  for (int j = 0; j < 5; j++) {
    float s = 0.f;
#pragma unroll
    for (int mm = 0; mm < 5; mm++) s += pr[mm] * s_corr[mm * 5 + j];
    co[j] = s;
  }
  float ref[5];
#pragma unroll
  for (int m = 0; m < 5; m++) ref[m] = s_cb2[m];
  for (int k = 0; k < 64; k++) {
    float h = s_cb1[k];
#pragma unroll
    for (int j = 0; j < 5; j++) h += co[j] * s_cw1[j * 64 + k];
    h = gelu_erf(h);
#pragma unroll
    for (int m = 0; m < 5; m++) ref[m] += h * s_cw2[k * 5 + m];
  }
  float sg = 1.f / (1.f + expf(-gate[0]));
#pragma unroll
  for (int m = 0; m < 5; m++) out[(size_t)t * 5 + m] = lg[m] + sg * ref[m];
}

extern "C" void kernel_launch(void* const* d_in, const int* in_sizes, int n_in,
                              void* d_out, int out_size, void* d_ws, size_t ws_size,
                              hipStream_t stream) {
  const float* h     = (const float*)d_in[0];
  const int*   mask  = (const int*)d_in[1];
  const float* W1    = (const float*)d_in[2];
  const float* b1    = (const float*)d_in[3];
  const float* W2    = (const float*)d_in[4];
  const float* b2    = (const float*)d_in[5];
  const float* W3    = (const float*)d_in[6];
  const float* b3    = (const float*)d_in[7];
  const float* gamma = (const float*)d_in[8];
  const float* wlog  = (const float*)d_in[9];
  const float* corr  = (const float*)d_in[10];
  const float* cw1   = (const float*)d_in[11];
  const float* cb1   = (const float*)d_in[12];
  const float* cw2   = (const float*)d_in[13];
  const float* cb2   = (const float*)d_in[14];
  const float* gate  = (const float*)d_in[15];
  float* out = (float*)d_out;

  char* ws = (char*)d_ws;
  unsigned short* hb  = (unsigned short*)(ws);
  unsigned short* W1t = (unsigned short*)(ws + 67108864);
  unsigned short* W2t = (unsigned short*)(ws + 72351744);
  unsigned short* t1  = (unsigned short*)(ws + 73662464);
  float* scores       = (float*)(ws + 241434624);
  float* logits       = (float*)(ws + 242089984);

  k_f32_to_bf16x4<<<33554432 / 4 / 256, 256, 0, stream>>>(h, hb, 33554432 / 4);
  k_transpose_tiled<<<dim3(16, 32, 5), 256, 0, stream>>>(W1, W1t, 1024, 512);
  k_transpose_tiled<<<dim3(8, 16, 5), 256, 0, stream>>>(W2, W2t, 512, 256);

  // GEMM1: hb[32768,1024] x W1t[2560,1024]^T -> t1 (gelu). NT=16.
  k_gemm256<false, 16><<<1280, 512, 0, stream>>>(
      hb, 1024, 0, W1t, 1024, b1, t1, 2560,
      nullptr, nullptr, nullptr, 10, 2560, 10);
  // GEMM2+scores: per m, t1[:, m*512 +: 512] x W2t_m^T -> gelu -> dot W3[m]. NT=8.
  k_gemm256<true, 8><<<640, 512, 0, stream>>>(
      t1, 2560, 512, W2t, 512, b2, nullptr, 0,
      W3, b3, scores, 1, 256, 5);

  k_span<<<dim3(16, 5), 256, 0, stream>>>(scores, mask, gamma, wlog, logits);
  k_cross<<<32768 / 256, 256, 0, stream>>>(logits, corr, cw1, cb1, cw2, cb2, gate, out);
}